// Round 11
// baseline (171.321 us; speedup 1.0000x reference)
//
#include <hip/hip_runtime.h>

typedef __attribute__((ext_vector_type(8))) short s16x8;
typedef __attribute__((ext_vector_type(4))) short s16x4;
typedef __attribute__((ext_vector_type(4))) float f32x4;
typedef __attribute__((ext_vector_type(2))) unsigned u32x2;

#define MFMA32(a, b, c) __builtin_amdgcn_mfma_f32_16x16x32_bf16((a), (b), (c), 0, 0, 0)

// Device pass on gfx950 has the 1k builtin (verified rounds 2-10). Host pass
// only parses device code, so stub it there.
#if __has_builtin(__builtin_amdgcn_mfma_f32_16x16x16bf16_1k)
#define MFMA16K(a, b, c) __builtin_amdgcn_mfma_f32_16x16x16bf16_1k((a), (b), (c), 0, 0, 0)
#else
#define MFMA16K(a, b, c) (c) /* host-pass parse stub; never executed */
#endif

#if __has_builtin(__builtin_amdgcn_exp2f)
#define EXP2F(x) __builtin_amdgcn_exp2f(x)
#else
#define EXP2F(x) __exp2f(x)
#endif

#if __has_builtin(__builtin_amdgcn_rcpf)
#define RCPF(x) __builtin_amdgcn_rcpf(x)
#else
#define RCPF(x) (1.0f / (x))
#endif

#define SL2E 0.25507313f  // (1/sqrt(32)) * log2(e)

// pack two f32 -> bf16 pair (RNE)
__device__ __forceinline__ unsigned pkrne(float a, float b) {
  unsigned ua = __builtin_bit_cast(unsigned, a);
  unsigned ub = __builtin_bit_cast(unsigned, b);
  ua += 0x7FFFu + ((ua >> 16) & 1u);
  ub += 0x7FFFu + ((ub >> 16) & 1u);
  return __builtin_amdgcn_perm(ub, ua, 0x07060302u);
}

// pack two f32 -> bf16 pair by TRUNCATION (1 v_perm); bias cancels in p/l
// because l comes from the same truncated P via ones-MFMA.
__device__ __forceinline__ unsigned pktrunc(float a, float b) {
  return __builtin_amdgcn_perm(__builtin_bit_cast(unsigned, b),
                               __builtin_bit_cast(unsigned, a), 0x07060302u);
}

__device__ __forceinline__ unsigned short bfr(float f) {
  unsigned u = __builtin_bit_cast(unsigned, f);
  u += 0x7FFFu + ((u >> 16) & 1u);
  return (unsigned short)(u >> 16);
}

// unpack bf16 pair -> f32
__device__ __forceinline__ float bflo(unsigned u) {
  return __builtin_bit_cast(float, u << 16);
}
__device__ __forceinline__ float bfhi(unsigned u) {
  return __builtin_bit_cast(float, u & 0xFFFF0000u);
}

// ---------------------------------------------------------------------------
// Prep: transpose+convert fp32 sources into bf16 k-contiguous layouts.
// ---------------------------------------------------------------------------
__global__ __launch_bounds__(256) void prep_kernel(
    const float* __restrict__ x, const float* __restrict__ wqkv,
    const float* __restrict__ wout, ushort* __restrict__ xbf,
    ushort* __restrict__ wT, ushort* __restrict__ woT) {
  const int t = threadIdx.x;
  const int sub = t & 15, grp = t >> 4;
  const int id = blockIdx.x;
  const float* src;
  ushort* dst;
  int src_ld, k0, n0;
  float sc = 1.f;
  if (id < 512) {
    int mt = id & 63, kt = (id >> 6) & 3, b = id >> 8;
    src = x + (size_t)b * 256 * 4096;
    src_ld = 4096;
    dst = xbf + (size_t)b * 4096 * 256;
    k0 = kt * 64;
    n0 = mt * 64;
  } else if (id < 560) {
    int r = id - 512, nt = r % 12, kt = r / 12;
    src = wqkv;
    src_ld = 768;
    dst = wT;
    k0 = kt * 64;
    n0 = nt * 64;
    if (n0 < 256) sc = SL2E;
  } else {
    int r = id - 560, nt = r & 3, kt = r >> 2;
    src = wout;
    src_ld = 256;
    dst = woT;
    k0 = kt * 64;
    n0 = nt * 64;
  }
  const int k = k0 + grp * 4;
  const int n = n0 + sub * 4;
  unsigned d0[4], d1[4];
#pragma unroll
  for (int i = 0; i < 4; ++i) {
    float4 v = *(const float4*)(src + (size_t)(k + i) * src_ld + n);
    d0[i] = pkrne(v.x * sc, v.y * sc);
    d1[i] = pkrne(v.z * sc, v.w * sc);
  }
  u32x2 r0 = {__builtin_amdgcn_perm(d0[1], d0[0], 0x05040100u),
              __builtin_amdgcn_perm(d0[3], d0[2], 0x05040100u)};
  u32x2 r1 = {__builtin_amdgcn_perm(d0[1], d0[0], 0x07060302u),
              __builtin_amdgcn_perm(d0[3], d0[2], 0x07060302u)};
  u32x2 r2 = {__builtin_amdgcn_perm(d1[1], d1[0], 0x05040100u),
              __builtin_amdgcn_perm(d1[3], d1[2], 0x05040100u)};
  u32x2 r3 = {__builtin_amdgcn_perm(d1[1], d1[0], 0x07060302u),
              __builtin_amdgcn_perm(d1[3], d1[2], 0x07060302u)};
  *(u32x2*)(dst + (size_t)(n + 0) * 256 + k) = r0;
  *(u32x2*)(dst + (size_t)(n + 1) * 256 + k) = r1;
  *(u32x2*)(dst + (size_t)(n + 2) * 256 + k) = r2;
  *(u32x2*)(dst + (size_t)(n + 3) * 256 + k) = r3;
}

// ---------------------------------------------------------------------------
// Fused QKV: D[n][tok] = wT(rows n) x xbf(rows tok). (unchanged, round 6)
// ---------------------------------------------------------------------------
__global__ __launch_bounds__(256) void qkv_kernel(
    const ushort* __restrict__ xbf, const ushort* __restrict__ wT,
    const float* __restrict__ bq, ushort* __restrict__ QG,
    ushort* __restrict__ KG, ushort* __restrict__ VtG) {
  __shared__ __align__(16) ushort Wl[64][40];
  __shared__ __align__(16) ushort Xl[128][40];
  const int t0 = blockIdx.x * 128;
  const int n0 = blockIdx.y * 64;
  const int t = threadIdx.x;
  const int wid = t >> 6, lane = t & 63;
  const int wy = wid >> 1, wx = wid & 1;
  const int quad = lane >> 4, l16 = lane & 15;
  f32x4 acc[2][4] = {};
  const int wr = t >> 2, wsg = t & 3;
  for (int k0 = 0; k0 < 256; k0 += 32) {
    __syncthreads();
    *(uint4*)&Wl[wr][wsg * 8] =
        *(const uint4*)(wT + (size_t)(n0 + wr) * 256 + k0 + wsg * 8);
#pragma unroll
    for (int i = 0; i < 2; ++i) {
      int fid = t + 256 * i, row = fid >> 2, seg = fid & 3;
      *(uint4*)&Xl[row][seg * 8] =
          *(const uint4*)(xbf + (size_t)(t0 + row) * 256 + k0 + seg * 8);
    }
    __syncthreads();
    s16x8 wf[2], xf[4];
#pragma unroll
    for (int i = 0; i < 2; ++i)
      wf[i] = *(const s16x8*)&Wl[32 * wy + 16 * i + l16][quad * 8];
#pragma unroll
    for (int j = 0; j < 4; ++j)
      xf[j] = *(const s16x8*)&Xl[64 * wx + 16 * j + l16][quad * 8];
#pragma unroll
    for (int i = 0; i < 2; ++i)
#pragma unroll
      for (int j = 0; j < 4; ++j) acc[i][j] = MFMA32(wf[i], xf[j], acc[i][j]);
  }
  if (n0 < 512) {
    ushort* dst = (n0 < 256) ? QG : KG;
    const float bsc = (n0 < 256) ? SL2E : 1.f;
#pragma unroll
    for (int i = 0; i < 2; ++i) {
      int nb = n0 + 32 * wy + 16 * i + 4 * quad;
      float4 b4 = *(const float4*)(bq + nb);
      float bx0 = b4.x * bsc, bx1 = b4.y * bsc, bx2 = b4.z * bsc,
            bx3 = b4.w * bsc;
      int h = ((nb & 255) >> 5);
      int dd0 = nb & 31;
#pragma unroll
      for (int j = 0; j < 4; ++j) {
        int tok = t0 + 64 * wx + 16 * j + l16;
        int b = tok >> 12, tokn = tok & 4095;
        u32x2 pk = {pkrne(acc[i][j][0] + bx0, acc[i][j][1] + bx1),
                    pkrne(acc[i][j][2] + bx2, acc[i][j][3] + bx3)};
        *(u32x2*)(dst + ((size_t)(b * 8 + h) * 4096 + tokn) * 32 + dd0) = pk;
      }
    }
  } else {
#pragma unroll
    for (int i = 0; i < 2; ++i) {
      int nb = n0 + 32 * wy + 16 * i + 4 * quad;
      float4 b4 = *(const float4*)(bq + nb);
      float bb[4] = {b4.x, b4.y, b4.z, b4.w};
#pragma unroll
      for (int r = 0; r < 4; ++r) {
        int nn = nb + r - 512;
        int h = nn >> 5, ddv = nn & 31;
        ushort* vrow = VtG + (size_t)(h * 32 + ddv) * 4096;
#pragma unroll
        for (int j = 0; j < 4; ++j) {
          int tok = t0 + 64 * wx + 16 * j + l16;
          int b = tok >> 12, tokn = tok & 4095;
          vrow[(size_t)b * 8 * 32 * 4096 + tokn] = bfr(acc[i][j][r] + bb[r]);
        }
      }
    }
  }
}

// ---------------------------------------------------------------------------
// Flash attention, SPLIT-K x4, 64 q-rows/wave, NO LDS / NO BARRIERS.
// K/V fragments are read per-wave directly from global (L2-resident: K+V =
// 1 MB per XCD-affine head pair; kf is a coalesced 1KB/instr read). Every
// wave is fully independent, and a per-block k-tile rotation (summation
// order free under no-max softmax) de-phases blocks so MFMA-phase/VALU-phase
// convoys can't form -- this tests whether r9/r10's "dur = VALU+MFMA sum"
// serialization was barrier-convoy (expect ~35us) or issue-port-structural
// (expect unchanged ~56us).
// ---------------------------------------------------------------------------
__global__ __launch_bounds__(256, 4) void attn_split(
    const ushort* __restrict__ QG, const ushort* __restrict__ KG,
    const ushort* __restrict__ VtG, ushort* __restrict__ OF0,
    ushort* __restrict__ OFb, float* __restrict__ LF) {
  const int id = blockIdx.x;
  const int bh = (id & 7) * 2 + ((id >> 3) & 1);  // XCD-affine heads
  const int q0 = ((id >> 4) & 15) * 256;
  const int sp = id >> 8;   // split index 0..3
  const int kt0 = sp * 16;
  const int rot = id & 15;  // de-phase: per-block k-tile rotation
  const int t = threadIdx.x;
  const int wid = t >> 6, lane = t & 63;
  const int quad = lane >> 4, l16 = lane & 15;
  const size_t base = (size_t)bh * 4096 * 32;
  const ushort* qp = QG + base;
  const ushort* kp = KG + base;
  const ushort* vp = VtG + base;
  const int qw = q0 + 64 * wid;
  s16x8 qf[4];
#pragma unroll
  for (int f = 0; f < 4; ++f)
    qf[f] = *(const s16x8*)(qp + (size_t)(qw + 16 * f + l16) * 32 + quad * 8);
  f32x4 oA[4], oB[4], ol[4];
#pragma unroll
  for (int f = 0; f < 4; ++f) {
    oA[f] = f32x4{};
    oB[f] = f32x4{};
    ol[f] = f32x4{};
  }
  const f32x4 zero = {};
  const s16x4 ones = {(short)0x3F80, (short)0x3F80, (short)0x3F80,
                      (short)0x3F80};
#pragma unroll 2
  for (int i = 0; i < 16; ++i) {
    const int kt = kt0 + ((i + rot) & 15);
    const ushort* kbase = kp + (size_t)kt * 64 * 32;
    const ushort* vbase = vp + kt * 64;
#pragma unroll
    for (int nb = 0; nb < 4; ++nb) {
      s16x8 kf =
          *(const s16x8*)(kbase + (size_t)(nb * 16 + l16) * 32 + quad * 8);
      s16x4 va =
          *(const s16x4*)(vbase + (size_t)l16 * 4096 + nb * 16 + quad * 4);
      s16x4 vb = *(const s16x4*)(vbase + (size_t)(16 + l16) * 4096 + nb * 16 +
                                 quad * 4);
#pragma unroll
      for (int f = 0; f < 4; ++f) {
        f32x4 s = MFMA32(kf, qf[f], zero);
        u32x2 pu = {pktrunc(EXP2F(s[0]), EXP2F(s[1])),
                    pktrunc(EXP2F(s[2]), EXP2F(s[3]))};
        s16x4 pv = __builtin_bit_cast(s16x4, pu);
        oA[f] = MFMA16K(va, pv, oA[f]);
        oB[f] = MFMA16K(vb, pv, oB[f]);
        ol[f] = MFMA16K(ones, pv, ol[f]);
      }
    }
  }
  // Store un-normalized bf16 partial O + f32 partial l.
  ushort* OFs = (sp == 0) ? OF0 : OFb + (size_t)(sp - 1) * 2097152;
  float* LFs = LF + (size_t)sp * 65536;
#pragma unroll
  for (int f = 0; f < 4; ++f) {
    const int tok = qw + 16 * f + l16;
    const size_t ob = ((size_t)bh * 4096 + tok) * 32;
    u32x2 wA = {pkrne(oA[f][0], oA[f][1]), pkrne(oA[f][2], oA[f][3])};
    u32x2 wB = {pkrne(oB[f][0], oB[f][1]), pkrne(oB[f][2], oB[f][3])};
    *(u32x2*)(OFs + ob + 4 * quad) = wA;
    *(u32x2*)(OFs + ob + 16 + 4 * quad) = wB;
    if (quad == 0) LFs[(size_t)bh * 4096 + tok] = ol[f][0];
  }
}

// ---------------------------------------------------------------------------
// Out-proj with fused 4-way split-combine + normalization in the staging.
// ---------------------------------------------------------------------------
__global__ __launch_bounds__(256) void proj_split(
    const ushort* __restrict__ OF0, const ushort* __restrict__ OFb,
    const float* __restrict__ LF, const ushort* __restrict__ woT,
    const float* __restrict__ bo, float* __restrict__ out) {
  __shared__ __align__(16) ushort Wl[64][40];
  __shared__ __align__(16) ushort Xl[128][40];
  const int t0 = blockIdx.x * 128;
  const int c0 = blockIdx.y * 64;
  const int t = threadIdx.x;
  const int wid = t >> 6, lane = t & 63;
  const int wy = wid >> 1, wx = wid & 1;
  const int quad = lane >> 4, l16 = lane & 15;
  f32x4 acc[2][4] = {};
  const int wr = t >> 2, wsg = t & 3;
  const int c8 = (t & 7) * 4;  // dd column (4 ushorts)
  for (int k0 = 0; k0 < 256; k0 += 32) {
    __syncthreads();
    *(uint4*)&Wl[wr][wsg * 8] =
        *(const uint4*)(woT + (size_t)(c0 + wr) * 256 + k0 + wsg * 8);
    const int hh = k0 >> 5;
#pragma unroll
    for (int p = 0; p < 4; ++p) {
      int row = 32 * p + (t >> 3);
      int tok = t0 + row, bb = tok >> 12, tokn = tok & 4095;
      size_t ro = (size_t)(bb * 8 + hh) * 4096 + tokn;
      size_t oi = ro * 32 + c8;
      uint2 a0 = *(const uint2*)(OF0 + oi);
      uint2 a1 = *(const uint2*)(OFb + oi);
      uint2 a2 = *(const uint2*)(OFb + 2097152 + oi);
      uint2 a3 = *(const uint2*)(OFb + 4194304 + oi);
      float l = (LF[ro] + LF[65536 + ro]) + (LF[131072 + ro] + LF[196608 + ro]);
      float inv = RCPF(l);
      f32x4 s;
      s[0] = (bflo(a0.x) + bflo(a1.x)) + (bflo(a2.x) + bflo(a3.x));
      s[1] = (bfhi(a0.x) + bfhi(a1.x)) + (bfhi(a2.x) + bfhi(a3.x));
      s[2] = (bflo(a0.y) + bflo(a1.y)) + (bflo(a2.y) + bflo(a3.y));
      s[3] = (bfhi(a0.y) + bfhi(a1.y)) + (bfhi(a2.y) + bfhi(a3.y));
      s *= inv;
      u32x2 pk = {pkrne(s[0], s[1]), pkrne(s[2], s[3])};
      *(u32x2*)&Xl[row][c8] = pk;
    }
    __syncthreads();
    s16x8 wf[2], xf[4];
#pragma unroll
    for (int i = 0; i < 2; ++i)
      wf[i] = *(const s16x8*)&Wl[32 * wy + 16 * i + l16][quad * 8];
#pragma unroll
    for (int j = 0; j < 4; ++j)
      xf[j] = *(const s16x8*)&Xl[64 * wx + 16 * j + l16][quad * 8];
#pragma unroll
    for (int i = 0; i < 2; ++i)
#pragma unroll
      for (int j = 0; j < 4; ++j) acc[i][j] = MFMA32(wf[i], xf[j], acc[i][j]);
  }
#pragma unroll
  for (int i = 0; i < 2; ++i) {
    int cb = c0 + 32 * wy + 16 * i + 4 * quad;
    float4 b4 = *(const float4*)(bo + cb);
    float bb[4] = {b4.x, b4.y, b4.z, b4.w};
#pragma unroll
    for (int j = 0; j < 4; ++j) {
      int tok = t0 + 64 * wx + 16 * j + l16;
      int b = tok >> 12, tokn = tok & 4095;
#pragma unroll
      for (int r = 0; r < 4; ++r)
        out[((size_t)(b * 256 + cb + r)) * 4096 + tokn] = acc[i][j][r] + bb[r];
    }
  }
}

extern "C" void kernel_launch(void* const* d_in, const int* in_sizes, int n_in,
                              void* d_out, int out_size, void* d_ws, size_t ws_size,
                              hipStream_t stream) {
  (void)in_sizes; (void)n_in; (void)out_size; (void)ws_size;
  const float* x = (const float*)d_in[0];
  const float* wq = (const float*)d_in[1];
  const float* bq = (const float*)d_in[2];
  const float* wo = (const float*)d_in[3];
  const float* bo = (const float*)d_in[4];
  float* out = (float*)d_out;
  ushort* ws = (ushort*)d_ws;
  // ws layout (30.9 MB; sufficiency verified round 8 ran this size):
  ushort* xbf = ws;                    // [8192][256]  (dead after qkv)
  ushort* OF0 = ws;                    // split0 partial O overlays dead xbf
  ushort* QG  = ws + 2097152;          // [2][8][4096][32]
  ushort* KG  = ws + 4194304;
  ushort* VtG = ws + 6291456;          // [2][8][32][4096]
  ushort* wT  = ws + 8388608;          // [768][256]
  ushort* woT = ws + 8585216;          // [256][256]
  ushort* OFb = ws + 8650752;          // splits 1..3: 3 x 2,097,152 ushorts
  float* LF = (float*)(ws + 14942208); // [4][16][4096] f32
  prep_kernel<<<576, 256, 0, stream>>>(x, wq, wo, xbf, wT, woT);
  qkv_kernel<<<dim3(64, 12), 256, 0, stream>>>(xbf, wT, bq, QG, KG, VtG);
  attn_split<<<1024, 256, 0, stream>>>(QG, KG, VtG, OF0, OFb, LF);
  proj_split<<<dim3(64, 4), 256, 0, stream>>>(OF0, OFb, LF, woT, bo, out);
}

// Round 12
// 142.128 us; speedup vs baseline: 1.2054x; 1.2054x over previous
//
#include <hip/hip_runtime.h>

typedef __attribute__((ext_vector_type(8))) short s16x8;
typedef __attribute__((ext_vector_type(4))) short s16x4;
typedef __attribute__((ext_vector_type(4))) float f32x4;
typedef __attribute__((ext_vector_type(2))) unsigned u32x2;

#define MFMA32(a, b, c) __builtin_amdgcn_mfma_f32_16x16x32_bf16((a), (b), (c), 0, 0, 0)

// Device pass on gfx950 has the 1k builtin (verified rounds 2-11). Host pass
// only parses device code, so stub it there.
#if __has_builtin(__builtin_amdgcn_mfma_f32_16x16x16bf16_1k)
#define MFMA16K(a, b, c) __builtin_amdgcn_mfma_f32_16x16x16bf16_1k((a), (b), (c), 0, 0, 0)
#else
#define MFMA16K(a, b, c) (c) /* host-pass parse stub; never executed */
#endif

#if __has_builtin(__builtin_amdgcn_exp2f)
#define EXP2F(x) __builtin_amdgcn_exp2f(x)
#else
#define EXP2F(x) __exp2f(x)
#endif

#if __has_builtin(__builtin_amdgcn_rcpf)
#define RCPF(x) __builtin_amdgcn_rcpf(x)
#else
#define RCPF(x) (1.0f / (x))
#endif

#define SL2E 0.25507313f  // (1/sqrt(32)) * log2(e)

// pack two f32 -> bf16 pair (RNE)
__device__ __forceinline__ unsigned pkrne(float a, float b) {
  unsigned ua = __builtin_bit_cast(unsigned, a);
  unsigned ub = __builtin_bit_cast(unsigned, b);
  ua += 0x7FFFu + ((ua >> 16) & 1u);
  ub += 0x7FFFu + ((ub >> 16) & 1u);
  return __builtin_amdgcn_perm(ub, ua, 0x07060302u);
}

// pack two f32 -> bf16 pair by TRUNCATION (1 v_perm); bias cancels in p/l
// because l comes from the same truncated P via ones-MFMA.
__device__ __forceinline__ unsigned pktrunc(float a, float b) {
  return __builtin_amdgcn_perm(__builtin_bit_cast(unsigned, b),
                               __builtin_bit_cast(unsigned, a), 0x07060302u);
}

__device__ __forceinline__ unsigned short bfr(float f) {
  unsigned u = __builtin_bit_cast(unsigned, f);
  u += 0x7FFFu + ((u >> 16) & 1u);
  return (unsigned short)(u >> 16);
}

// unpack bf16 pair -> f32
__device__ __forceinline__ float bflo(unsigned u) {
  return __builtin_bit_cast(float, u << 16);
}
__device__ __forceinline__ float bfhi(unsigned u) {
  return __builtin_bit_cast(float, u & 0xFFFF0000u);
}

// ---------------------------------------------------------------------------
// Prep: transpose+convert fp32 sources into bf16 k-contiguous layouts.
// ---------------------------------------------------------------------------
__global__ __launch_bounds__(256) void prep_kernel(
    const float* __restrict__ x, const float* __restrict__ wqkv,
    const float* __restrict__ wout, ushort* __restrict__ xbf,
    ushort* __restrict__ wT, ushort* __restrict__ woT) {
  const int t = threadIdx.x;
  const int sub = t & 15, grp = t >> 4;
  const int id = blockIdx.x;
  const float* src;
  ushort* dst;
  int src_ld, k0, n0;
  float sc = 1.f;
  if (id < 512) {
    int mt = id & 63, kt = (id >> 6) & 3, b = id >> 8;
    src = x + (size_t)b * 256 * 4096;
    src_ld = 4096;
    dst = xbf + (size_t)b * 4096 * 256;
    k0 = kt * 64;
    n0 = mt * 64;
  } else if (id < 560) {
    int r = id - 512, nt = r % 12, kt = r / 12;
    src = wqkv;
    src_ld = 768;
    dst = wT;
    k0 = kt * 64;
    n0 = nt * 64;
    if (n0 < 256) sc = SL2E;
  } else {
    int r = id - 560, nt = r & 3, kt = r >> 2;
    src = wout;
    src_ld = 256;
    dst = woT;
    k0 = kt * 64;
    n0 = nt * 64;
  }
  const int k = k0 + grp * 4;
  const int n = n0 + sub * 4;
  unsigned d0[4], d1[4];
#pragma unroll
  for (int i = 0; i < 4; ++i) {
    float4 v = *(const float4*)(src + (size_t)(k + i) * src_ld + n);
    d0[i] = pkrne(v.x * sc, v.y * sc);
    d1[i] = pkrne(v.z * sc, v.w * sc);
  }
  u32x2 r0 = {__builtin_amdgcn_perm(d0[1], d0[0], 0x05040100u),
              __builtin_amdgcn_perm(d0[3], d0[2], 0x05040100u)};
  u32x2 r1 = {__builtin_amdgcn_perm(d0[1], d0[0], 0x07060302u),
              __builtin_amdgcn_perm(d0[3], d0[2], 0x07060302u)};
  u32x2 r2 = {__builtin_amdgcn_perm(d1[1], d1[0], 0x05040100u),
              __builtin_amdgcn_perm(d1[3], d1[2], 0x05040100u)};
  u32x2 r3 = {__builtin_amdgcn_perm(d1[1], d1[0], 0x07060302u),
              __builtin_amdgcn_perm(d1[3], d1[2], 0x07060302u)};
  *(u32x2*)(dst + (size_t)(n + 0) * 256 + k) = r0;
  *(u32x2*)(dst + (size_t)(n + 1) * 256 + k) = r1;
  *(u32x2*)(dst + (size_t)(n + 2) * 256 + k) = r2;
  *(u32x2*)(dst + (size_t)(n + 3) * 256 + k) = r3;
}

// ---------------------------------------------------------------------------
// Fused QKV: D[n][tok] = wT(rows n) x xbf(rows tok). (unchanged, round 6)
// ---------------------------------------------------------------------------
__global__ __launch_bounds__(256) void qkv_kernel(
    const ushort* __restrict__ xbf, const ushort* __restrict__ wT,
    const float* __restrict__ bq, ushort* __restrict__ QG,
    ushort* __restrict__ KG, ushort* __restrict__ VtG) {
  __shared__ __align__(16) ushort Wl[64][40];
  __shared__ __align__(16) ushort Xl[128][40];
  const int t0 = blockIdx.x * 128;
  const int n0 = blockIdx.y * 64;
  const int t = threadIdx.x;
  const int wid = t >> 6, lane = t & 63;
  const int wy = wid >> 1, wx = wid & 1;
  const int quad = lane >> 4, l16 = lane & 15;
  f32x4 acc[2][4] = {};
  const int wr = t >> 2, wsg = t & 3;
  for (int k0 = 0; k0 < 256; k0 += 32) {
    __syncthreads();
    *(uint4*)&Wl[wr][wsg * 8] =
        *(const uint4*)(wT + (size_t)(n0 + wr) * 256 + k0 + wsg * 8);
#pragma unroll
    for (int i = 0; i < 2; ++i) {
      int fid = t + 256 * i, row = fid >> 2, seg = fid & 3;
      *(uint4*)&Xl[row][seg * 8] =
          *(const uint4*)(xbf + (size_t)(t0 + row) * 256 + k0 + seg * 8);
    }
    __syncthreads();
    s16x8 wf[2], xf[4];
#pragma unroll
    for (int i = 0; i < 2; ++i)
      wf[i] = *(const s16x8*)&Wl[32 * wy + 16 * i + l16][quad * 8];
#pragma unroll
    for (int j = 0; j < 4; ++j)
      xf[j] = *(const s16x8*)&Xl[64 * wx + 16 * j + l16][quad * 8];
#pragma unroll
    for (int i = 0; i < 2; ++i)
#pragma unroll
      for (int j = 0; j < 4; ++j) acc[i][j] = MFMA32(wf[i], xf[j], acc[i][j]);
  }
  if (n0 < 512) {
    ushort* dst = (n0 < 256) ? QG : KG;
    const float bsc = (n0 < 256) ? SL2E : 1.f;
#pragma unroll
    for (int i = 0; i < 2; ++i) {
      int nb = n0 + 32 * wy + 16 * i + 4 * quad;
      float4 b4 = *(const float4*)(bq + nb);
      float bx0 = b4.x * bsc, bx1 = b4.y * bsc, bx2 = b4.z * bsc,
            bx3 = b4.w * bsc;
      int h = ((nb & 255) >> 5);
      int dd0 = nb & 31;
#pragma unroll
      for (int j = 0; j < 4; ++j) {
        int tok = t0 + 64 * wx + 16 * j + l16;
        int b = tok >> 12, tokn = tok & 4095;
        u32x2 pk = {pkrne(acc[i][j][0] + bx0, acc[i][j][1] + bx1),
                    pkrne(acc[i][j][2] + bx2, acc[i][j][3] + bx3)};
        *(u32x2*)(dst + ((size_t)(b * 8 + h) * 4096 + tokn) * 32 + dd0) = pk;
      }
    }
  } else {
#pragma unroll
    for (int i = 0; i < 2; ++i) {
      int nb = n0 + 32 * wy + 16 * i + 4 * quad;
      float4 b4 = *(const float4*)(bq + nb);
      float bb[4] = {b4.x, b4.y, b4.z, b4.w};
#pragma unroll
      for (int r = 0; r < 4; ++r) {
        int nn = nb + r - 512;
        int h = nn >> 5, ddv = nn & 31;
        ushort* vrow = VtG + (size_t)(h * 32 + ddv) * 4096;
#pragma unroll
        for (int j = 0; j < 4; ++j) {
          int tok = t0 + 64 * wx + 16 * j + l16;
          int b = tok >> 12, tokn = tok & 4095;
          vrow[(size_t)b * 8 * 32 * 4096 + tokn] = bfr(acc[i][j][r] + bb[r]);
        }
      }
    }
  }
}

// ---------------------------------------------------------------------------
// Flash attention, SPLIT-K x3, 64 q-rows/wave, LDS double-buffered K/V
// (r9/r10 best-known structure) + SCHEDULING HEADROOM: launch_bounds(256,3)
// gives ~170-reg budget (vs 128 at (256,4)); the nb-group is restructured as
// [4 independent MFMA32s] -> [16 exps] -> [12 MFMA16Ks] so QK-MFMAs of the
// next group can issue under the exp/PV of the current one. Tests the
// latency-bound hypothesis from r11 (global-read version regressed ->
// chain latency, not convoy/issue-port, is the 56us plateau's cause).
// Grid 768 = 3 blocks/CU exactly. No-max softmax => partials additive.
// ---------------------------------------------------------------------------
__global__ __launch_bounds__(256, 3) void attn_split(
    const ushort* __restrict__ QG, const ushort* __restrict__ KG,
    const ushort* __restrict__ VtG, ushort* __restrict__ OF0,
    ushort* __restrict__ OFb, float* __restrict__ LF) {
  __shared__ __align__(16) ushort Kl[2][64][40];
  __shared__ __align__(16) ushort Vl[2][32][72];
  const int id = blockIdx.x;
  const int bh = (id & 7) * 2 + ((id >> 3) & 1);  // XCD-affine heads
  const int q0 = ((id >> 4) & 15) * 256;
  const int sp = id >> 8;                          // split index 0..2
  const int kt0 = (sp * 64 + 2) / 3;               // {0,22,43}
  const int niter = ((sp + 1) * 64 + 2) / 3 - kt0; // {22,21,21}
  const int t = threadIdx.x;
  const int wid = t >> 6, lane = t & 63;
  const int quad = lane >> 4, l16 = lane & 15;
  const size_t base = (size_t)bh * 4096 * 32;
  const ushort* qp = QG + base;
  const ushort* kp = KG + base;
  const ushort* vp = VtG + base;
  const int qw = q0 + 64 * wid;
  s16x8 qf[4];
#pragma unroll
  for (int f = 0; f < 4; ++f)
    qf[f] = *(const s16x8*)(qp + (size_t)(qw + 16 * f + l16) * 32 + quad * 8);
  const int kr = t >> 2, ks = t & 3;
  const int vr = t >> 3, vsg = t & 7;
  *(uint4*)&Kl[0][kr][ks * 8] =
      *(const uint4*)(kp + (size_t)(kt0 * 64 + kr) * 32 + ks * 8);
  *(uint4*)&Vl[0][vr][vsg * 8] =
      *(const uint4*)(vp + (size_t)vr * 4096 + kt0 * 64 + vsg * 8);
  const ushort* kpre = kp + (size_t)((kt0 + 1) * 64 + kr) * 32 + ks * 8;
  const ushort* vpre = vp + (size_t)vr * 4096 + (kt0 + 1) * 64 + vsg * 8;
  __syncthreads();
  f32x4 oA[4], oB[4], ol[4];
#pragma unroll
  for (int f = 0; f < 4; ++f) {
    oA[f] = f32x4{};
    oB[f] = f32x4{};
    ol[f] = f32x4{};
  }
  const f32x4 zero = {};
  const s16x4 ones = {(short)0x3F80, (short)0x3F80, (short)0x3F80,
                      (short)0x3F80};
  for (int i = 0; i < niter; ++i) {
    const int cur = i & 1;
    const bool more = (i + 1) < niter;
    uint4 kv, vv;
    if (more) {
      kv = *(const uint4*)kpre;
      vv = *(const uint4*)vpre;
      kpre += 2048;
      vpre += 64;
    }
#pragma unroll
    for (int nb = 0; nb < 4; ++nb) {
      s16x8 kf = *(const s16x8*)&Kl[cur][16 * nb + l16][quad * 8];
      s16x4 va = *(const s16x4*)&Vl[cur][l16][16 * nb + quad * 4];
      s16x4 vb = *(const s16x4*)&Vl[cur][16 + l16][16 * nb + quad * 4];
      // Phase 1: all 4 independent QK-MFMAs (schedulable early)
      f32x4 s[4];
#pragma unroll
      for (int f = 0; f < 4; ++f) s[f] = MFMA32(kf, qf[f], zero);
      // Phase 2: all 16 exps + 8 packs
      s16x4 pv[4];
#pragma unroll
      for (int f = 0; f < 4; ++f) {
        u32x2 pu = {pktrunc(EXP2F(s[f][0]), EXP2F(s[f][1])),
                    pktrunc(EXP2F(s[f][2]), EXP2F(s[f][3]))};
        pv[f] = __builtin_bit_cast(s16x4, pu);
      }
      // Phase 3: all 12 PV/l MFMAs
#pragma unroll
      for (int f = 0; f < 4; ++f) {
        oA[f] = MFMA16K(va, pv[f], oA[f]);
        oB[f] = MFMA16K(vb, pv[f], oB[f]);
        ol[f] = MFMA16K(ones, pv[f], ol[f]);
      }
    }
    if (more) {
      *(uint4*)&Kl[cur ^ 1][kr][ks * 8] = kv;
      *(uint4*)&Vl[cur ^ 1][vr][vsg * 8] = vv;
    }
    __syncthreads();
  }
  // Store un-normalized bf16 partial O + f32 partial l.
  ushort* OFs = (sp == 0) ? OF0 : OFb + (size_t)(sp - 1) * 2097152;
  float* LFs = LF + (size_t)sp * 65536;
#pragma unroll
  for (int f = 0; f < 4; ++f) {
    const int tok = qw + 16 * f + l16;
    const size_t ob = ((size_t)bh * 4096 + tok) * 32;
    u32x2 wA = {pkrne(oA[f][0], oA[f][1]), pkrne(oA[f][2], oA[f][3])};
    u32x2 wB = {pkrne(oB[f][0], oB[f][1]), pkrne(oB[f][2], oB[f][3])};
    *(u32x2*)(OFs + ob + 4 * quad) = wA;
    *(u32x2*)(OFs + ob + 16 + 4 * quad) = wB;
    if (quad == 0) LFs[(size_t)bh * 4096 + tok] = ol[f][0];
  }
}

// ---------------------------------------------------------------------------
// Out-proj with fused 3-way split-combine + normalization in the staging.
// ---------------------------------------------------------------------------
__global__ __launch_bounds__(256) void proj_split(
    const ushort* __restrict__ OF0, const ushort* __restrict__ OFb,
    const float* __restrict__ LF, const ushort* __restrict__ woT,
    const float* __restrict__ bo, float* __restrict__ out) {
  __shared__ __align__(16) ushort Wl[64][40];
  __shared__ __align__(16) ushort Xl[128][40];
  const int t0 = blockIdx.x * 128;
  const int c0 = blockIdx.y * 64;
  const int t = threadIdx.x;
  const int wid = t >> 6, lane = t & 63;
  const int wy = wid >> 1, wx = wid & 1;
  const int quad = lane >> 4, l16 = lane & 15;
  f32x4 acc[2][4] = {};
  const int wr = t >> 2, wsg = t & 3;
  const int c8 = (t & 7) * 4;  // dd column (4 ushorts)
  for (int k0 = 0; k0 < 256; k0 += 32) {
    __syncthreads();
    *(uint4*)&Wl[wr][wsg * 8] =
        *(const uint4*)(woT + (size_t)(c0 + wr) * 256 + k0 + wsg * 8);
    const int hh = k0 >> 5;
#pragma unroll
    for (int p = 0; p < 4; ++p) {
      int row = 32 * p + (t >> 3);
      int tok = t0 + row, bb = tok >> 12, tokn = tok & 4095;
      size_t ro = (size_t)(bb * 8 + hh) * 4096 + tokn;
      size_t oi = ro * 32 + c8;
      uint2 a0 = *(const uint2*)(OF0 + oi);
      uint2 a1 = *(const uint2*)(OFb + oi);
      uint2 a2 = *(const uint2*)(OFb + 2097152 + oi);
      float l = LF[ro] + LF[65536 + ro] + LF[131072 + ro];
      float inv = RCPF(l);
      f32x4 s;
      s[0] = bflo(a0.x) + bflo(a1.x) + bflo(a2.x);
      s[1] = bfhi(a0.x) + bfhi(a1.x) + bfhi(a2.x);
      s[2] = bflo(a0.y) + bflo(a1.y) + bflo(a2.y);
      s[3] = bfhi(a0.y) + bfhi(a1.y) + bfhi(a2.y);
      s *= inv;
      u32x2 pk = {pkrne(s[0], s[1]), pkrne(s[2], s[3])};
      *(u32x2*)&Xl[row][c8] = pk;
    }
    __syncthreads();
    s16x8 wf[2], xf[4];
#pragma unroll
    for (int i = 0; i < 2; ++i)
      wf[i] = *(const s16x8*)&Wl[32 * wy + 16 * i + l16][quad * 8];
#pragma unroll
    for (int j = 0; j < 4; ++j)
      xf[j] = *(const s16x8*)&Xl[64 * wx + 16 * j + l16][quad * 8];
#pragma unroll
    for (int i = 0; i < 2; ++i)
#pragma unroll
      for (int j = 0; j < 4; ++j) acc[i][j] = MFMA32(wf[i], xf[j], acc[i][j]);
  }
#pragma unroll
  for (int i = 0; i < 2; ++i) {
    int cb = c0 + 32 * wy + 16 * i + 4 * quad;
    float4 b4 = *(const float4*)(bo + cb);
    float bb[4] = {b4.x, b4.y, b4.z, b4.w};
#pragma unroll
    for (int j = 0; j < 4; ++j) {
      int tok = t0 + 64 * wx + 16 * j + l16;
      int b = tok >> 12, tokn = tok & 4095;
#pragma unroll
      for (int r = 0; r < 4; ++r)
        out[((size_t)(b * 256 + cb + r)) * 4096 + tokn] = acc[i][j][r] + bb[r];
    }
  }
}

extern "C" void kernel_launch(void* const* d_in, const int* in_sizes, int n_in,
                              void* d_out, int out_size, void* d_ws, size_t ws_size,
                              hipStream_t stream) {
  (void)in_sizes; (void)n_in; (void)out_size; (void)ws_size;
  const float* x = (const float*)d_in[0];
  const float* wq = (const float*)d_in[1];
  const float* bq = (const float*)d_in[2];
  const float* wo = (const float*)d_in[3];
  const float* bo = (const float*)d_in[4];
  float* out = (float*)d_out;
  ushort* ws = (ushort*)d_ws;
  // ws layout (26.5 MB; sufficiency verified rounds 7-10):
  ushort* xbf = ws;                    // [8192][256]  (dead after qkv)
  ushort* OF0 = ws;                    // split0 partial O overlays dead xbf
  ushort* QG  = ws + 2097152;          // [2][8][4096][32]
  ushort* KG  = ws + 4194304;
  ushort* VtG = ws + 6291456;          // [2][8][32][4096]
  ushort* wT  = ws + 8388608;          // [768][256]
  ushort* woT = ws + 8585216;          // [256][256]
  ushort* OFb = ws + 8650752;          // splits 1,2: 2 x 2,097,152 ushorts
  float* LF = (float*)(ws + 12845056); // [3][16][4096] f32
  prep_kernel<<<576, 256, 0, stream>>>(x, wq, wo, xbf, wT, woT);
  qkv_kernel<<<dim3(64, 12), 256, 0, stream>>>(xbf, wT, bq, QG, KG, VtG);
  attn_split<<<768, 256, 0, stream>>>(QG, KG, VtG, OF0, OFb, LF);
  proj_split<<<dim3(64, 4), 256, 0, stream>>>(OF0, OFb, LF, woT, bo, out);
}